// Round 2
// baseline (2353.740 us; speedup 1.0000x reference)
//
#include <hip/hip_runtime.h>

typedef __bf16 bf16;
typedef __bf16 bf16x8 __attribute__((ext_vector_type(8)));
typedef __bf16 bf16x4 __attribute__((ext_vector_type(4)));
typedef float f32x4 __attribute__((ext_vector_type(4)));

__device__ inline f32x4 mfma16(bf16x8 a, bf16x8 b, f32x4 c) {
    return __builtin_amdgcn_mfma_f32_16x16x32_bf16(a, b, c, 0, 0, 0);
}

__device__ inline bf16x8 cvt8(const float* p) {
    float4 f0 = *(const float4*)p;
    float4 f1 = *(const float4*)(p + 4);
    bf16x8 t;
    t[0] = (bf16)f0.x; t[1] = (bf16)f0.y; t[2] = (bf16)f0.z; t[3] = (bf16)f0.w;
    t[4] = (bf16)f1.x; t[5] = (bf16)f1.y; t[6] = (bf16)f1.z; t[7] = (bf16)f1.w;
    return t;
}

// ---------------------------------------------------------------------------
// GEMM: C(MxN) = A(MxK)bf16 @ B(NxK)f32^T, f32 accum.
// EPI: 0 = f32 out, 1 = f32 out + residual add
// 128x128 tile, BK=32, 256 threads (4 waves, 2x2 of 64x64), LDS pad +8.
// ---------------------------------------------------------------------------
template <int EPI>
__global__ __launch_bounds__(256) void gemm_kernel(
    const bf16* __restrict__ A, const float* __restrict__ Bm,
    const float* __restrict__ res, float* __restrict__ Cout,
    int M, int N, int K)
{
    __shared__ bf16 As[128 * 40];
    __shared__ bf16 Bs[128 * 40];
    const int tid = threadIdx.x;
    const int wave = tid >> 6, lane = tid & 63;
    const int quad = lane >> 4, l16 = lane & 15;
    const int row0 = blockIdx.y * 128, col0 = blockIdx.x * 128;
    const int wrow = (wave >> 1) * 64, wcol = (wave & 1) * 64;

    f32x4 acc[4][4] = {};

    const int lr = tid >> 2;          // 0..63
    const int lc = (tid & 3) * 8;     // 0,8,16,24
    const bf16*  Ag = A  + (size_t)(row0 + lr) * K + lc;
    const float* Bg = Bm + (size_t)(col0 + lr) * K + lc;

    for (int kb = 0; kb < K; kb += 32) {
        *(bf16x8*)(&As[lr * 40 + lc])        = *(const bf16x8*)(Ag + kb);
        *(bf16x8*)(&As[(64 + lr) * 40 + lc]) = *(const bf16x8*)(Ag + (size_t)64 * K + kb);
        *(bf16x8*)(&Bs[lr * 40 + lc])        = cvt8(Bg + kb);
        *(bf16x8*)(&Bs[(64 + lr) * 40 + lc]) = cvt8(Bg + (size_t)64 * K + kb);
        __syncthreads();
        bf16x8 af[4], bfr[4];
#pragma unroll
        for (int i = 0; i < 4; ++i)
            af[i] = *(const bf16x8*)(&As[(wrow + i * 16 + l16) * 40 + quad * 8]);
#pragma unroll
        for (int j = 0; j < 4; ++j)
            bfr[j] = *(const bf16x8*)(&Bs[(wcol + j * 16 + l16) * 40 + quad * 8]);
#pragma unroll
        for (int i = 0; i < 4; ++i)
#pragma unroll
            for (int j = 0; j < 4; ++j)
                acc[i][j] = mfma16(af[i], bfr[j], acc[i][j]);
        __syncthreads();
    }

#pragma unroll
    for (int i = 0; i < 4; ++i) {
        const int row = row0 + wrow + i * 16 + quad * 4;
#pragma unroll
        for (int j = 0; j < 4; ++j) {
            const int col = col0 + wcol + j * 16 + l16;
#pragma unroll
            for (int r = 0; r < 4; ++r) {
                const size_t idx = (size_t)(row + r) * N + col;
                float v = acc[i][j][r];
                if (EPI == 1) Cout[idx] = v + res[idx];
                else          Cout[idx] = v;
            }
        }
    }
}

// ---------------------------------------------------------------------------
// prenorm+concat: xcat[row,0:1024]=rmsnorm(emb), [1024:2048]=rmsnorm(hid)
// one wave per (row, half); f32 in, bf16 out
// ---------------------------------------------------------------------------
__global__ __launch_bounds__(256) void prenorm_kernel(
    const float* __restrict__ emb, const float* __restrict__ hid,
    const float* __restrict__ we, const float* __restrict__ wh,
    bf16* __restrict__ xcat)
{
    const int rr = blockIdx.x * 4 + (threadIdx.x >> 6);
    const int lane = threadIdx.x & 63;
    const int half = rr & 1, row = rr >> 1;
    const float* x = (half ? hid : emb) + (size_t)row * 1024;
    const float* w = half ? wh : we;
    float4 v[4]; float ss = 0.f;
#pragma unroll
    for (int j = 0; j < 4; ++j) {
        v[j] = *(const float4*)(x + (size_t)(lane + 64 * j) * 4);
        ss += v[j].x * v[j].x + v[j].y * v[j].y + v[j].z * v[j].z + v[j].w * v[j].w;
    }
#pragma unroll
    for (int m = 32; m; m >>= 1) ss += __shfl_xor(ss, m, 64);
    const float rms = rsqrtf(ss * (1.f / 1024.f) + 1e-6f);
    bf16* o = xcat + (size_t)row * 2048 + half * 1024;
#pragma unroll
    for (int j = 0; j < 4; ++j) {
        const int d = (lane + 64 * j) * 4;
        float4 wv = *(const float4*)(w + d);
        bf16x4 t;
        t[0] = (bf16)(v[j].x * rms * wv.x);
        t[1] = (bf16)(v[j].y * rms * wv.y);
        t[2] = (bf16)(v[j].z * rms * wv.z);
        t[3] = (bf16)(v[j].w * rms * wv.w);
        *(bf16x4*)(o + d) = t;
    }
}

// rmsnorm over H=1024, f32 in -> bf16 out, one wave per row
__global__ __launch_bounds__(256) void rmsnorm_kernel(
    const float* __restrict__ xin, const float* __restrict__ w, bf16* __restrict__ out)
{
    const int row = blockIdx.x * 4 + (threadIdx.x >> 6);
    const int lane = threadIdx.x & 63;
    const float* x = xin + (size_t)row * 1024;
    float4 v[4]; float ss = 0.f;
#pragma unroll
    for (int j = 0; j < 4; ++j) {
        v[j] = *(const float4*)(x + (size_t)(lane + 64 * j) * 4);
        ss += v[j].x * v[j].x + v[j].y * v[j].y + v[j].z * v[j].z + v[j].w * v[j].w;
    }
#pragma unroll
    for (int m = 32; m; m >>= 1) ss += __shfl_xor(ss, m, 64);
    const float rms = rsqrtf(ss * (1.f / 1024.f) + 1e-6f);
    bf16* o = out + (size_t)row * 1024;
#pragma unroll
    for (int j = 0; j < 4; ++j) {
        const int d = (lane + 64 * j) * 4;
        float4 wv = *(const float4*)(w + d);
        bf16x4 t;
        t[0] = (bf16)(v[j].x * rms * wv.x);
        t[1] = (bf16)(v[j].y * rms * wv.y);
        t[2] = (bf16)(v[j].z * rms * wv.z);
        t[3] = (bf16)(v[j].w * rms * wv.w);
        *(bf16x4*)(o + d) = t;
    }
}

// ---------------------------------------------------------------------------
// q prep: rmsnorm(D=256) -> rope(first 64, interleaved) -> *1/16 -> bf16
// layout (B,L,NQ,2,D) f32  ->  (B,NQ,L,D) bf16. One wave per (b,l,h) row.
// ---------------------------------------------------------------------------
__global__ __launch_bounds__(256) void qprep_kernel(
    const float* __restrict__ qg, const float* __restrict__ qn_w, bf16* __restrict__ qa)
{
    const int row = blockIdx.x * 4 + (threadIdx.x >> 6);  // (b*L+l)*8+h
    const int lane = threadIdx.x & 63;
    const int h = row & 7, bl = row >> 3;
    const int l = bl & 2047, b = bl >> 11;
    const float* x = qg + (size_t)row * 512;
    float v[4]; float ss = 0.f;
#pragma unroll
    for (int j = 0; j < 4; ++j) { v[j] = x[lane + 64 * j]; ss += v[j] * v[j]; }
#pragma unroll
    for (int m = 32; m; m >>= 1) ss += __shfl_xor(ss, m, 64);
    const float rms = rsqrtf(ss * (1.f / 256.f) + 1e-6f);
    float y[4];
#pragma unroll
    for (int j = 0; j < 4; ++j) y[j] = v[j] * rms * qn_w[lane + 64 * j];
    { // rope: d<64 is exactly j==0 (d = lane)
        const float p = __shfl_xor(y[0], 1, 64);
        const int i2 = lane >> 1;
        const float inv = powf(1e7f, -(float)(2 * i2) * (1.f / 64.f));
        const float ang = (float)l * inv;
        const float c = cosf(ang), s = sinf(ang);
        y[0] = (lane & 1) ? (p * s + y[0] * c) : (y[0] * c - p * s);
    }
    bf16* o = qa + ((size_t)((b * 8 + h) * 2048 + l)) * 256;
#pragma unroll
    for (int j = 0; j < 4; ++j) o[lane + 64 * j] = (bf16)(y[j] * 0.0625f);
}

// k prep: same minus scale; (B,L,NKV,D) f32 -> (B,NKV,L,D) bf16
__global__ __launch_bounds__(256) void kprep_kernel(
    const float* __restrict__ kf, const float* __restrict__ kn_w, bf16* __restrict__ ka)
{
    const int row = blockIdx.x * 4 + (threadIdx.x >> 6);  // (b*L+l)*2+kv
    const int lane = threadIdx.x & 63;
    const int kv = row & 1, bl = row >> 1;
    const int l = bl & 2047, b = bl >> 11;
    const float* x = kf + (size_t)row * 256;
    float v[4]; float ss = 0.f;
#pragma unroll
    for (int j = 0; j < 4; ++j) { v[j] = x[lane + 64 * j]; ss += v[j] * v[j]; }
#pragma unroll
    for (int m = 32; m; m >>= 1) ss += __shfl_xor(ss, m, 64);
    const float rms = rsqrtf(ss * (1.f / 256.f) + 1e-6f);
    float y[4];
#pragma unroll
    for (int j = 0; j < 4; ++j) y[j] = v[j] * rms * kn_w[lane + 64 * j];
    {
        const float p = __shfl_xor(y[0], 1, 64);
        const int i2 = lane >> 1;
        const float inv = powf(1e7f, -(float)(2 * i2) * (1.f / 64.f));
        const float ang = (float)l * inv;
        const float c = cosf(ang), s = sinf(ang);
        y[0] = (lane & 1) ? (p * s + y[0] * c) : (y[0] * c - p * s);
    }
    bf16* o = ka + ((size_t)((b * 2 + kv) * 2048 + l)) * 256;
#pragma unroll
    for (int j = 0; j < 4; ++j) o[lane + 64 * j] = (bf16)y[j];
}

// v prep: (B,L,NKV,D) f32 -> (B,NKV,D,L) bf16 (transposed for attention B-frags)
__global__ void vprep_kernel(const float* __restrict__ vf, bf16* __restrict__ vt)
{
    const size_t i = (size_t)blockIdx.x * 256 + threadIdx.x;  // 4,194,304
    const int l = (int)(i & 2047);
    const int d = (int)((i >> 11) & 255);
    const int kv = (int)((i >> 19) & 1);
    const int b = (int)(i >> 20);
    vt[i] = (bf16)vf[(((size_t)(b * 2048 + l) * 2 + kv) * 256) + d];
}

// ---------------------------------------------------------------------------
// flash attention: 1 block = (b, h, 64 q-rows); 4 waves x 16 rows.
// Q pre-scaled by 1/16. Causal. of: (B,NQ,L,D) f32.
// ---------------------------------------------------------------------------
__global__ __launch_bounds__(256) void attn_kernel(
    const bf16* __restrict__ qa, const bf16* __restrict__ ka,
    const bf16* __restrict__ vt, float* __restrict__ of)
{
    __shared__ bf16 Ks[32 * 264];    // 32 kv x 256 d (+8 pad)
    __shared__ bf16 Vt[256 * 40];    // 256 d x 32 kv (+8 pad)
    __shared__ bf16 Pw[4 * 16 * 40]; // per-wave 16 x 32 (+8 pad)
    const int tid = threadIdx.x;
    const int wave = tid >> 6, lane = tid & 63;
    const int quad = lane >> 4, l16 = lane & 15;
    const int bid = blockIdx.x;
    const int qt = bid & 31, h = (bid >> 5) & 7, b = bid >> 8;
    const int kvh = h >> 2;
    const bf16* qptr = qa + ((size_t)(b * 8 + h)) * 2048 * 256;
    const bf16* kptr = ka + ((size_t)(b * 2 + kvh)) * 2048 * 256;
    const bf16* vptr = vt + ((size_t)(b * 2 + kvh)) * 256 * 2048;
    const int qbase = qt * 64 + wave * 16;

    bf16x8 qf[8];
#pragma unroll
    for (int db = 0; db < 8; ++db)
        qf[db] = *(const bf16x8*)(qptr + (size_t)(qbase + l16) * 256 + db * 32 + quad * 8);

    f32x4 o_acc[16] = {};
    float m_i[4], l_i[4];
#pragma unroll
    for (int r = 0; r < 4; ++r) { m_i[r] = -1e30f; l_i[r] = 0.f; }

    const int ntiles = qt * 2 + 2;
    for (int kt = 0; kt < ntiles; ++kt) {
        const int kvs = kt * 32;
#pragma unroll
        for (int c = 0; c < 4; ++c) {
            const int idx = tid + c * 256;
            const int kr = idx >> 5, kc = (idx & 31) * 8;
            *(bf16x8*)(&Ks[kr * 264 + kc]) = *(const bf16x8*)(kptr + (size_t)(kvs + kr) * 256 + kc);
            const int vd = idx >> 2, vc = (idx & 3) * 8;
            *(bf16x8*)(&Vt[vd * 40 + vc]) = *(const bf16x8*)(vptr + (size_t)vd * 2048 + kvs + vc);
        }
        __syncthreads();

        f32x4 s0 = {}, s1 = {};
#pragma unroll
        for (int db = 0; db < 8; ++db) {
            bf16x8 k0 = *(const bf16x8*)(&Ks[l16 * 264 + db * 32 + quad * 8]);
            bf16x8 k1 = *(const bf16x8*)(&Ks[(16 + l16) * 264 + db * 32 + quad * 8]);
            s0 = mfma16(qf[db], k0, s0);
            s1 = mfma16(qf[db], k1, s1);
        }

        float alpha[4], p0v[4], p1v[4];
#pragma unroll
        for (int r = 0; r < 4; ++r) {
            const int qrow = qbase + quad * 4 + r;
            float a0 = (kvs + l16 > qrow) ? -1e30f : s0[r];
            float a1 = (kvs + 16 + l16 > qrow) ? -1e30f : s1[r];
            float mx = fmaxf(a0, a1);
#pragma unroll
            for (int m = 8; m; m >>= 1) mx = fmaxf(mx, __shfl_xor(mx, m, 64));
            const float mnew = fmaxf(m_i[r], mx);
            const float a = __expf(m_i[r] - mnew);
            const float p0 = __expf(a0 - mnew);
            const float p1 = __expf(a1 - mnew);
            float ps = p0 + p1;
#pragma unroll
            for (int m = 8; m; m >>= 1) ps += __shfl_xor(ps, m, 64);
            l_i[r] = l_i[r] * a + ps;
            m_i[r] = mnew;
            alpha[r] = a; p0v[r] = p0; p1v[r] = p1;
        }
#pragma unroll
        for (int t = 0; t < 16; ++t) {
            f32x4 o = o_acc[t];
            o[0] *= alpha[0]; o[1] *= alpha[1]; o[2] *= alpha[2]; o[3] *= alpha[3];
            o_acc[t] = o;
        }
        bf16* pw = &Pw[wave * 16 * 40];
#pragma unroll
        for (int r = 0; r < 4; ++r) {
            pw[(quad * 4 + r) * 40 + l16]      = (bf16)p0v[r];
            pw[(quad * 4 + r) * 40 + 16 + l16] = (bf16)p1v[r];
        }
        __syncthreads();
        const bf16x8 pa = *(const bf16x8*)(&pw[l16 * 40 + quad * 8]);
#pragma unroll
        for (int t = 0; t < 16; ++t) {
            bf16x8 vfr = *(const bf16x8*)(&Vt[(t * 16 + l16) * 40 + quad * 8]);
            o_acc[t] = mfma16(pa, vfr, o_acc[t]);
        }
        __syncthreads();
    }

    float* optr = of + ((size_t)(b * 8 + h)) * 2048 * 256;
#pragma unroll
    for (int r = 0; r < 4; ++r) {
        const float inv = 1.f / l_i[r];
        const int row = qbase + quad * 4 + r;
#pragma unroll
        for (int t = 0; t < 16; ++t)
            optr[(size_t)row * 256 + t * 16 + l16] = o_acc[t][r] * inv;
    }
}

// gated output: ag[(b,l,h*256+d)] = of[(b,h,l,d)] * sigmoid(qg gate)
__global__ void gating_kernel(const float* __restrict__ of, const float* __restrict__ qg,
                              bf16* __restrict__ ag)
{
    const size_t i = (size_t)blockIdx.x * 256 + threadIdx.x;  // 16,777,216
    const int d = (int)(i & 255);
    const int h = (int)((i >> 8) & 7);
    const size_t bl = i >> 11;
    const float o = of[((size_t)((bl >> 11) * 8 + h) * 2048 + (bl & 2047)) * 256 + d];
    const float g = qg[(bl * 8 + h) * 512 + 256 + d];
    ag[i] = (bf16)(o * (1.f / (1.f + __expf(-g))));
}

// h = bf16(silu(g) * u)
__global__ void silu_kernel(const float* __restrict__ g, const float* __restrict__ u,
                            bf16* __restrict__ h)
{
    const size_t i = ((size_t)blockIdx.x * 256 + threadIdx.x) * 4;
    const float4 gv = *(const float4*)(g + i);
    const float4 uv = *(const float4*)(u + i);
    bf16x4 t;
    t[0] = (bf16)(gv.x * (1.f / (1.f + __expf(-gv.x))) * uv.x);
    t[1] = (bf16)(gv.y * (1.f / (1.f + __expf(-gv.y))) * uv.y);
    t[2] = (bf16)(gv.z * (1.f / (1.f + __expf(-gv.z))) * uv.z);
    t[3] = (bf16)(gv.w * (1.f / (1.f + __expf(-gv.w))) * uv.w);
    *(bf16x4*)(h + i) = t;
}

// ---------------------------------------------------------------------------
extern "C" void kernel_launch(void* const* d_in, const int* in_sizes, int n_in,
                              void* d_out, int out_size, void* d_ws, size_t ws_size,
                              hipStream_t stream)
{
    const float* emb       = (const float*)d_in[0];
    const float* hid       = (const float*)d_in[1];
    const float* pre_emb_w = (const float*)d_in[2];
    const float* pre_hid_w = (const float*)d_in[3];
    const float* fc_w      = (const float*)d_in[4];
    const float* in_ln_w   = (const float*)d_in[5];
    const float* q_w       = (const float*)d_in[6];
    const float* k_w       = (const float*)d_in[7];
    const float* v_w       = (const float*)d_in[8];
    const float* o_w       = (const float*)d_in[9];
    const float* qn_w      = (const float*)d_in[10];
    const float* kn_w      = (const float*)d_in[11];
    const float* post_ln_w = (const float*)d_in[12];
    const float* gate_w    = (const float*)d_in[13];
    const float* up_w      = (const float*)d_in[14];
    const float* down_w    = (const float*)d_in[15];
    const float* norm_w    = (const float*)d_in[16];
    const float* lm_w      = (const float*)d_in[17];
    float* out = (float*)d_out;
    char* ws = (char*)d_ws;

    // workspace layout (lifetime-overlapped), total 360 MiB
    float* xres = (float*)(ws + 0);                 // 32 MiB, residual (in-place updated)
    bf16*  xln  = (bf16*)(ws + 33554432);           // 16 MiB, reused 3x
    char*  C    = ws + 50331648;                    // 128 MiB: qg then gate_f32
    char*  D    = ws + 184549376;                   // 128 MiB: xcat/kf/vf/of then up_f32
    char*  E    = ws + 318767104;                   // 56 MiB: qa/ka/va then ag then h
    float* qg   = (float*)C;
    float* gf   = (float*)C;
    bf16*  xcat = (bf16*)D;
    float* kf   = (float*)(D + 33554432);
    float* vf   = (float*)(D + 50331648);
    float* of   = (float*)(D + 67108864);
    float* uf   = (float*)D;
    bf16*  qa   = (bf16*)E;
    bf16*  ka   = (bf16*)(E + 33554432);
    bf16*  va   = (bf16*)(E + 41943040);
    bf16*  ag   = (bf16*)E;
    bf16*  hb   = (bf16*)E;

    prenorm_kernel<<<4096, 256, 0, stream>>>(emb, hid, pre_emb_w, pre_hid_w, xcat);
    gemm_kernel<0><<<dim3(8, 64), 256, 0, stream>>>(xcat, fc_w, nullptr, xres, 8192, 1024, 2048);
    rmsnorm_kernel<<<2048, 256, 0, stream>>>(xres, in_ln_w, xln);
    gemm_kernel<0><<<dim3(32, 64), 256, 0, stream>>>(xln, q_w, nullptr, qg, 8192, 4096, 1024);
    gemm_kernel<0><<<dim3(4, 64), 256, 0, stream>>>(xln, k_w, nullptr, kf, 8192, 512, 1024);
    gemm_kernel<0><<<dim3(4, 64), 256, 0, stream>>>(xln, v_w, nullptr, vf, 8192, 512, 1024);
    qprep_kernel<<<16384, 256, 0, stream>>>(qg, qn_w, qa);
    kprep_kernel<<<4096, 256, 0, stream>>>(kf, kn_w, ka);
    vprep_kernel<<<16384, 256, 0, stream>>>(vf, va);
    attn_kernel<<<1024, 256, 0, stream>>>(qa, ka, va, of);
    gating_kernel<<<65536, 256, 0, stream>>>(of, qg, ag);
    gemm_kernel<1><<<dim3(8, 64), 256, 0, stream>>>(ag, o_w, xres, xres, 8192, 1024, 2048);
    rmsnorm_kernel<<<2048, 256, 0, stream>>>(xres, post_ln_w, xln);
    gemm_kernel<0><<<dim3(28, 64), 256, 0, stream>>>(xln, gate_w, nullptr, gf, 8192, 3584, 1024);
    gemm_kernel<0><<<dim3(28, 64), 256, 0, stream>>>(xln, up_w, nullptr, uf, 8192, 3584, 1024);
    silu_kernel<<<28672, 256, 0, stream>>>(gf, uf, hb);
    gemm_kernel<1><<<dim3(8, 64), 256, 0, stream>>>(hb, down_w, xres, xres, 8192, 1024, 3584);
    rmsnorm_kernel<<<2048, 256, 0, stream>>>(xres, norm_w, xln);
    gemm_kernel<0><<<dim3(128, 64), 256, 0, stream>>>(xln, lm_w, nullptr, out, 8192, 16384, 1024);
}